// Round 1
// 542.911 us; speedup vs baseline: 1.0464x; 1.0464x over previous
//
#include <hip/hip_runtime.h>

// SelfAttnPool: B=32, T=4096, F=512, U=512 (fp32 in/out)
//   scores[b,t] = tanh(x[b,t,:]@W + b) @ V   (u never materialized)
//   a = softmax_T(scores); out[b,f] = sum_t a[b,t]*x[b,t,f]
//
// R5: cooperative LDS A-staging + double-buffered software pipeline.
//   - Previously every x element was loaded + cvt_hilo-split 4x (once per
//     wc wave). Now all 512 threads stage the 128x16 K-slice once into a
//     fragment-ready bf16 hi/lo LDS buffer (16 KB, double-buffered), and
//     waves ds_read_b128 their A-frags (lane-linear, conflict-free).
//   - 2-deep register prefetch of the next x slices (1 float4/thread),
//     issued AFTER the B loads so MFMA's vmcnt wait leaves it in flight.
//   - Numerics unchanged: same cvt_hilo splits, same MFMA accumulation
//     order per acc -> bit-identical scores.

#define XT 4096
#define XF 512
#define XU 512

typedef __attribute__((ext_vector_type(8))) short short8;
typedef __attribute__((ext_vector_type(4))) short sh4;
typedef __attribute__((ext_vector_type(16))) float f32x16;

__device__ inline void cvt_hilo(float x, unsigned short &h, unsigned short &l) {
  unsigned u = __builtin_bit_cast(unsigned, x);
  h = (unsigned short)(u >> 16);                       // truncated bf16 hi
  float hf = __builtin_bit_cast(float, u & 0xFFFF0000u);
  float lo = x - hf;                                   // exact residual
  l = (unsigned short)(__builtin_bit_cast(unsigned, lo) >> 16);
}

__device__ inline float tanh_fast(float z) {
  float e = __expf(2.0f * z);
  return 1.0f - 2.0f * __builtin_amdgcn_rcpf(e + 1.0f);
}

// ---- W pre-conversion: fp32 [512 k][512 n] -> bf16 hi/lo, fragment-ready:
// whi/wlo: [slice s(32)][chunk16B: t(16)*64 + g(2)*32 + l(32)][j(8)]
// element = W[k = s*16 + g*8 + j][n = t*32 + l]
__global__ void wconv_kernel(const float *__restrict__ W,
                             unsigned short *__restrict__ whi,
                             unsigned short *__restrict__ wlo) {
  int t2 = blockIdx.x * 256 + threadIdx.x;  // 32768 threads
  int l = t2 & 31;
  int g = (t2 >> 5) & 1;
  int t = (t2 >> 6) & 15;
  int s = t2 >> 10;
  short8 hv, lv;
#pragma unroll
  for (int j = 0; j < 8; ++j) {
    unsigned short h, lo;
    cvt_hilo(W[(size_t)(s * 16 + g * 8 + j) * XU + t * 32 + l], h, lo);
    hv[j] = (short)h;
    lv[j] = (short)lo;
  }
  size_t off = (size_t)s * 8192 + t * 512 + g * 256 + l * 8;
  *(short8 *)(whi + off) = hv;
  *(short8 *)(wlo + off) = lv;
}

#define MFMA(a, b, c) __builtin_amdgcn_mfma_f32_32x32x16_bf16(a, b, c, 0, 0, 0)

// ---- fused GEMM + tanh + (.@V) + chunk-local softmax + weighted pooling
// block: 512 thr = 8 waves; tile 128 rows x 512 cols (one chunk of one batch).
// Emits partial[block][512] and pstats[block] = (m_c, l_c).
__global__ __launch_bounds__(512, 2)
void gemm_scores_kernel(const float *__restrict__ x,
                        const unsigned short *__restrict__ whi,
                        const unsigned short *__restrict__ wlo,
                        const float *__restrict__ bias,
                        const float *__restrict__ V,
                        float *__restrict__ partial,
                        float *__restrict__ pstats) {
  // A staging: [buf 2][rowgroup 4][hi/lo 2][512 ushort] = 16 KB.
  // Within a (rg,hl) 1KB block: ushort idx = (k>>3)*256 + (row&31)*8 + (k&7)
  // -> wave frag read at byte lane*16 is contiguous / conflict-free.
  __shared__ unsigned short Abuf[2][4][2][512];
  __shared__ float scb[512];   // per-wave-quarter partial scores
  __shared__ float warr[128];  // chunk-local softmax weights e^{s-m}
  __shared__ float red[1536];  // pooling cross-rowgroup reduction
  __shared__ float sarr[128];

  const int tid = threadIdx.x;
  const int lane = tid & 63;
  const int wave = tid >> 6;
  const int wr = wave >> 2;   // row half (64 rows)
  const int wc = wave & 3;    // col quarter (128 cols)
  const int l31 = lane & 31;
  const int half = lane >> 5;
  const size_t rowbase = (size_t)blockIdx.x * 128;

  f32x16 acc[2][4];
#pragma unroll
  for (int a = 0; a < 2; ++a)
#pragma unroll
    for (int c = 0; c < 4; ++c)
#pragma unroll
      for (int r = 0; r < 16; ++r) acc[a][c][r] = 0.f;

  // ---- staging mapping: thread -> (row, k-quad) of the 128x16 slice
  const int srow = tid >> 2;  // 0..127
  const int sq = tid & 3;     // k-quad (4 floats)
  const float *sx = x + (rowbase + srow) * XF + sq * 4;
  const int widx = (sq >> 1) * 256 + (srow & 31) * 8 + (sq & 1) * 4;
  unsigned short *wb0 = &Abuf[0][srow >> 5][0][widx];
  unsigned short *wb1 = &Abuf[1][srow >> 5][0][widx];

  auto stage = [&](unsigned short *wb, float4 v) {
    sh4 h, l;
    unsigned short hh, ll;
    cvt_hilo(v.x, hh, ll); h[0] = (short)hh; l[0] = (short)ll;
    cvt_hilo(v.y, hh, ll); h[1] = (short)hh; l[1] = (short)ll;
    cvt_hilo(v.z, hh, ll); h[2] = (short)hh; l[2] = (short)ll;
    cvt_hilo(v.w, hh, ll); h[3] = (short)hh; l[3] = (short)ll;
    *(sh4 *)wb = h;
    *(sh4 *)(wb + 512) = l;  // lo block is +512 ushorts
  };

  const unsigned short *whp = whi + (size_t)(wc * 4) * 512 + lane * 8;
  const unsigned short *wlp = wlo + (size_t)(wc * 4) * 512 + lane * 8;

  // ---- prologue: stage slice 0 into buf0, issue prefetch of slice 1
  float4 xv = *(const float4 *)(sx);
  stage(wb0, xv);
  float4 xa = *(const float4 *)(sx + 16);
  __syncthreads();

#pragma unroll 2
  for (int s = 0; s < 32; ++s) {
    const int cur = s & 1;
    // B fragments first (so the MFMA vmcnt wait doesn't drain the x prefetch)
    const unsigned short *p = whp + (size_t)s * 8192;
    const unsigned short *q = wlp + (size_t)s * 8192;
    short8 bh[4], bl[4];
#pragma unroll
    for (int cf = 0; cf < 4; ++cf) {
      bh[cf] = *(const short8 *)(p + cf * 512);
      bl[cf] = *(const short8 *)(q + cf * 512);
    }
    // A fragments from LDS (lane-linear, conflict-free b128)
    const unsigned short *ab0 = &Abuf[cur][wr * 2 + 0][0][0] + lane * 8;
    const unsigned short *ab1 = &Abuf[cur][wr * 2 + 1][0][0] + lane * 8;
    short8 ah0 = *(const short8 *)(ab0);
    short8 al0 = *(const short8 *)(ab0 + 512);
    short8 ah1 = *(const short8 *)(ab1);
    short8 al1 = *(const short8 *)(ab1 + 512);

    // 2-ahead x prefetch (kept in flight across the MFMA block + barrier)
    float4 xb = xa;
    if (s < 30) xb = *(const float4 *)(sx + (s + 2) * 16);

#pragma unroll
    for (int cf = 0; cf < 4; ++cf) {
      acc[0][cf] = MFMA(ah0, bh[cf], acc[0][cf]);
      acc[1][cf] = MFMA(ah1, bh[cf], acc[1][cf]);
      acc[0][cf] = MFMA(al0, bh[cf], acc[0][cf]);
      acc[1][cf] = MFMA(al1, bh[cf], acc[1][cf]);
      acc[0][cf] = MFMA(ah0, bl[cf], acc[0][cf]);
      acc[1][cf] = MFMA(ah1, bl[cf], acc[1][cf]);
    }

    // stage next slice into the other buffer (xa completed long ago)
    if (s < 31) stage(cur ? wb0 : wb1, xa);
    __syncthreads();
    xa = xb;
  }

  // ---- score epilogue: sc[row] = sum_n tanh(acc + b[n]) * V[n]
  // C/D 32x32: col n = l31 (+32*cf+128*wc); row = (r&3)+8*(r>>2)+4*half (+32*rf+64*wr)
  float sc[2][16];
#pragma unroll
  for (int rf = 0; rf < 2; ++rf)
#pragma unroll
    for (int r = 0; r < 16; ++r) sc[rf][r] = 0.f;

#pragma unroll
  for (int cf = 0; cf < 4; ++cf) {
    int n = wc * 128 + cf * 32 + l31;
    float vv = V[n];
    float bb = bias[n];
#pragma unroll
    for (int rf = 0; rf < 2; ++rf)
#pragma unroll
      for (int r = 0; r < 16; ++r)
        sc[rf][r] += tanh_fast(acc[rf][cf][r] + bb) * vv;
  }
#pragma unroll
  for (int m = 1; m <= 16; m <<= 1) {
#pragma unroll
    for (int rf = 0; rf < 2; ++rf)
#pragma unroll
      for (int r = 0; r < 16; ++r)
        sc[rf][r] += __shfl_xor(sc[rf][r], m, 64);
  }
  if (l31 == 0) {
#pragma unroll
    for (int rf = 0; rf < 2; ++rf)
#pragma unroll
      for (int r = 0; r < 16; ++r) {
        int row = wr * 64 + rf * 32 + (r & 3) + 8 * (r >> 2) + 4 * half;
        scb[wc * 128 + row] = sc[rf][r];
      }
  }
  __syncthreads();

  // ---- chunk-local softmax: s_t -> m_c, w_t = e^{s_t - m_c}
  if (tid < 128)
    sarr[tid] = scb[tid] + scb[128 + tid] + scb[256 + tid] + scb[384 + tid];
  __syncthreads();
  float mloc = -1e30f;
#pragma unroll 8
  for (int i = 0; i < 128; ++i) mloc = fmaxf(mloc, sarr[i]);
  if (tid < 128) warr[tid] = __expf(sarr[tid] - mloc);
  __syncthreads();

  // l_c = sum warr : 64-lane shuffle reduce (replaces serial tid==0 loop)
  float lsum = 0.f;
  if (tid < 64) {
    lsum = warr[tid] + warr[tid + 64];
#pragma unroll
    for (int m = 1; m < 64; m <<= 1) lsum += __shfl_xor(lsum, m, 64);
  }

  // ---- weighted pooling over own (L2-hot) tile: 4 row-groups x 128 col4s
  const int rg = tid >> 7;   // 0..3 -> rows rg*32..+32
  const int c4 = tid & 127;  // float4 column
  const float *xp = x + rowbase * XF;
  float4 pa = {0.f, 0.f, 0.f, 0.f};
#pragma unroll 8
  for (int i = 0; i < 32; ++i) {
    int r = rg * 32 + i;
    float4 v = *(const float4 *)(xp + (size_t)r * XF + c4 * 4);
    float wv = warr[r];
    pa.x += wv * v.x;
    pa.y += wv * v.y;
    pa.z += wv * v.z;
    pa.w += wv * v.w;
  }
  if (rg > 0) {
    float *rp = red + (rg - 1) * 512 + c4 * 4;
    rp[0] = pa.x; rp[1] = pa.y; rp[2] = pa.z; rp[3] = pa.w;
  }
  __syncthreads();
  if (rg == 0) {
    const float *r0 = red + c4 * 4;
    float4 o;
    o.x = pa.x + r0[0] + r0[512] + r0[1024];
    o.y = pa.y + r0[1] + r0[513] + r0[1025];
    o.z = pa.z + r0[2] + r0[514] + r0[1026];
    o.w = pa.w + r0[3] + r0[515] + r0[1027];
    *(float4 *)(partial + (size_t)blockIdx.x * 512 + c4 * 4) = o;
  }
  if (tid == 0) {
    pstats[blockIdx.x * 2] = mloc;
    pstats[blockIdx.x * 2 + 1] = lsum;
  }
}

// ---- combine: out[b,f] = sum_c e^{m_c-M} partial[c][f] / (sum_c e^{m_c-M} l_c)
__global__ __launch_bounds__(512)
void combine_kernel(const float *__restrict__ partial,
                    const float *__restrict__ pstats,
                    float *__restrict__ out) {
  int b = blockIdx.x;
  int f = threadIdx.x;
  __shared__ float ml[32], ll[32];
  if (f < 32) {
    ml[f] = pstats[(b * 32 + f) * 2];
    ll[f] = pstats[(b * 32 + f) * 2 + 1];
  }
  __syncthreads();
  float M = -1e30f;
#pragma unroll
  for (int c = 0; c < 32; ++c) M = fmaxf(M, ml[c]);
  float L = 0.f;
#pragma unroll
  for (int c = 0; c < 32; ++c) L += __expf(ml[c] - M) * ll[c];
  float acc = 0.f;
#pragma unroll
  for (int c = 0; c < 32; ++c)
    acc += __expf(ml[c] - M) * partial[(size_t)(b * 32 + c) * 512 + f];
  out[b * XF + f] = acc / L;
}

extern "C" void kernel_launch(void *const *d_in, const int *in_sizes, int n_in,
                              void *d_out, int out_size, void *d_ws,
                              size_t ws_size, hipStream_t stream) {
  const float *x = (const float *)d_in[0];
  const float *W = (const float *)d_in[1];
  const float *bias = (const float *)d_in[2];
  const float *V = (const float *)d_in[3];
  float *out = (float *)d_out;

  // workspace: whi 512KB | wlo 512KB | partial 2MB | pstats 8KB
  unsigned short *whi = (unsigned short *)d_ws;
  unsigned short *wlo = whi + 262144;
  float *partial = (float *)((char *)d_ws + 1048576);
  float *pstats = (float *)((char *)d_ws + 1048576 + 2097152);

  wconv_kernel<<<128, 256, 0, stream>>>(W, whi, wlo);
  gemm_scores_kernel<<<1024, 512, 0, stream>>>(x, whi, wlo, bias, V, partial,
                                               pstats);
  combine_kernel<<<32, 512, 0, stream>>>(partial, pstats, out);
}